// Round 2
// baseline (151.420 us; speedup 1.0000x reference)
//
#include <hip/hip_runtime.h>
#include <hip/hip_cooperative_groups.h>
#include <math.h>

namespace cg = cooperative_groups;

// MultiChannelXi: xi[b,t,k,:] = sum_{s<=t} alpha_k^(t-s) h[b,s,:] / Z_{k,t}
// alpha = clip(sigmoid(raw_alpha), 1e-6, 1-1e-6),
// Z_{k,t} = (1 - alpha^(t+1)) / (1 - alpha).
// Single cooperative kernel: chunked scan with register-resident h chunk.
//   phase 1 : per-chunk weighted sums L  (h -> VGPRs, reused in phase 3)
//   phase 2a: per-group (8 chunks) sums G
//   phase 2b: per-block prefix from <=15 G's + <=7 L's (fully parallel)
//   phase 3 : in-chunk rescan + normalize + store

namespace {

constexpr int T_LEN  = 4096;
constexpr int D_DIM  = 512;
constexpr int D4     = D_DIM / 4;      // 128 float4 lanes
constexpr int K_CH   = 4;
constexpr int CHUNK  = 32;
constexpr int NCHUNK = T_LEN / CHUNK;  // 128
constexpr int GRP    = 8;
constexpr int NGRP   = NCHUNK / GRP;   // 16

__device__ __forceinline__ float sigmoid_clip(float x) {
    float a = 1.0f / (1.0f + expf(-x));
    return fminf(fmaxf(a, 1e-6f), 1.0f - 1e-6f);
}

__device__ __forceinline__ void fma4(float4& d, float a, const float4& x) {
    d.x = fmaf(a, d.x, x.x);
    d.y = fmaf(a, d.y, x.y);
    d.z = fmaf(a, d.z, x.z);
    d.w = fmaf(a, d.w, x.w);
}

__global__ void __launch_bounds__(128, 2)
ema_fused(const float4* __restrict__ h4,
          const float*  __restrict__ raw_alpha,
          float4* __restrict__ lbuf,   // [B][NCHUNK][K][D4]
          float4* __restrict__ gbuf,   // [B][NGRP][K][D4]
          float4* __restrict__ out4,   // [B][T][K][D4]
          int B)
{
    cg::grid_group grid = cg::this_grid();
    const int c  = blockIdx.x % NCHUNK;
    const int b  = blockIdx.x / NCHUNK;
    const int d4 = threadIdx.x;
    const int t0 = c * CHUNK;

    float al[K_CH], aC[K_CH];
#pragma unroll
    for (int k = 0; k < K_CH; ++k) {
        al[k] = sigmoid_clip(raw_alpha[k]);
        aC[k] = exp2f((float)CHUNK * log2f(al[k]));   // alpha^CHUNK
    }

    // ---- phase 1: h chunk -> registers; chunk-weighted sums ----
    float4 hreg[CHUNK];
    {
        const float4* hp = h4 + ((size_t)b * T_LEN + t0) * D4 + d4;
#pragma unroll
        for (int j = 0; j < CHUNK; ++j) hreg[j] = hp[(size_t)j * D4];
    }
    {
        float4 L[K_CH];
#pragma unroll
        for (int k = 0; k < K_CH; ++k) L[k] = make_float4(0.f, 0.f, 0.f, 0.f);
#pragma unroll
        for (int j = 0; j < CHUNK; ++j) {
#pragma unroll
            for (int k = 0; k < K_CH; ++k) fma4(L[k], al[k], hreg[j]);
        }
#pragma unroll
        for (int k = 0; k < K_CH; ++k)
            lbuf[(((size_t)b * NCHUNK + c) * K_CH + k) * D4 + d4] = L[k];
    }

    grid.sync();

    // ---- phase 2a: group sums G[b][g] = sum_i aC^(GRP-1-i) * L[b][g*GRP+i] ----
    if (blockIdx.x < (unsigned)(B * NGRP)) {
        const int g  = blockIdx.x % NGRP;
        const int bb = blockIdx.x / NGRP;
        float4 G[K_CH];
#pragma unroll
        for (int k = 0; k < K_CH; ++k) G[k] = make_float4(0.f, 0.f, 0.f, 0.f);
        for (int i = 0; i < GRP; ++i) {
            const int cp = g * GRP + i;
#pragma unroll
            for (int k = 0; k < K_CH; ++k) {
                float4 Lv = lbuf[(((size_t)bb * NCHUNK + cp) * K_CH + k) * D4 + d4];
                fma4(G[k], aC[k], Lv);
            }
        }
#pragma unroll
        for (int k = 0; k < K_CH; ++k)
            gbuf[(((size_t)bb * NGRP + g) * K_CH + k) * D4 + d4] = G[k];
    }

    grid.sync();

    // ---- phase 2b: prefix state entering chunk c ----
    float4 S[K_CH];
#pragma unroll
    for (int k = 0; k < K_CH; ++k) S[k] = make_float4(0.f, 0.f, 0.f, 0.f);
    {
        const int g = c / GRP;
        float aG[K_CH];
#pragma unroll
        for (int k = 0; k < K_CH; ++k)
            aG[k] = exp2f((float)(CHUNK * GRP) * log2f(al[k]));  // alpha^(CHUNK*GRP)
        for (int gp = 0; gp < g; ++gp) {          // state after group g-1
#pragma unroll
            for (int k = 0; k < K_CH; ++k) {
                float4 Gv = gbuf[(((size_t)b * NGRP + gp) * K_CH + k) * D4 + d4];
                fma4(S[k], aG[k], Gv);
            }
        }
        for (int cp = g * GRP; cp < c; ++cp) {    // remaining chunks in group
#pragma unroll
            for (int k = 0; k < K_CH; ++k) {
                float4 Lv = lbuf[(((size_t)b * NCHUNK + cp) * K_CH + k) * D4 + d4];
                fma4(S[k], aC[k], Lv);
            }
        }
    }

    // ---- phase 3: in-chunk rescan + normalize + store ----
    float om[K_CH], pw[K_CH];
#pragma unroll
    for (int k = 0; k < K_CH; ++k) {
        om[k] = 1.0f - al[k];
        pw[k] = exp2f((float)(t0 + 1) * log2f(al[k]));  // alpha^(t+1) at j=0
    }
    float4* op = out4 + (((size_t)b * T_LEN + t0) * (size_t)K_CH) * D4 + d4;
#pragma unroll
    for (int j = 0; j < CHUNK; ++j) {
#pragma unroll
        for (int k = 0; k < K_CH; ++k) {
            fma4(S[k], al[k], hreg[j]);
            const float invZ = om[k] / fmaxf(1.0f - pw[k], 1e-30f);
            float4 o;
            o.x = S[k].x * invZ;
            o.y = S[k].y * invZ;
            o.z = S[k].z * invZ;
            o.w = S[k].w * invZ;
            op[((size_t)j * K_CH + k) * D4] = o;
            pw[k] *= al[k];
        }
    }
}

} // namespace

extern "C" void kernel_launch(void* const* d_in, const int* in_sizes, int n_in,
                              void* d_out, int out_size, void* d_ws, size_t ws_size,
                              hipStream_t stream)
{
    const float4* h4        = (const float4*)d_in[0];
    const float*  raw_alpha = (const float*)d_in[1];
    float4* out4 = (float4*)d_out;

    int B = in_sizes[0] / (T_LEN * D_DIM);  // 4

    float4* lbuf = (float4*)d_ws;                          // B*NCHUNK*K*D4 float4 = 4 MB
    float4* gbuf = lbuf + (size_t)B * NCHUNK * K_CH * D4;  // B*NGRP*K*D4 float4 = 512 KB

    void* kargs[] = { (void*)&h4, (void*)&raw_alpha, (void*)&lbuf,
                      (void*)&gbuf, (void*)&out4, (void*)&B };
    hipLaunchCooperativeKernel((void*)ema_fused, dim3(B * NCHUNK), dim3(D4),
                               kargs, 0, stream);
}

// Round 3
// 78.746 us; speedup vs baseline: 1.9229x; 1.9229x over previous
//
#include <hip/hip_runtime.h>
#include <math.h>

// MultiChannelXi: xi[b,t,k,:] = sum_{s<=t} alpha_k^(t-s) h[b,s,:] / Z_{k,t}
// alpha = clip(sigmoid(raw_alpha), 1e-6, 1-1e-6),
// Z_{k,t} = (1 - alpha^(t+1)) / (1 - alpha).
//
// 2-kernel chunked scan:
//   k1: per-chunk weighted sums L[b,c,k,:]  (streams h once)
//   k2: per-(b,c) block derives its own entering state directly from
//       L[b,0..c-1,k,:] (L2-resident, weighted by aC^(c-1-cp)), then
//       rescans its h chunk, normalizes, writes out.
// No serial inter-chunk kernel; no grid.sync; no register-resident h.

namespace {

constexpr int T_LEN  = 4096;
constexpr int D_DIM  = 512;
constexpr int D4     = D_DIM / 4;      // 128 float4 lanes per row
constexpr int K_CH   = 4;
constexpr int CHUNK  = 32;
constexpr int NCHUNK = T_LEN / CHUNK;  // 128

__device__ __forceinline__ float sigmoid_clip(float x) {
    float a = 1.0f / (1.0f + expf(-x));
    return fminf(fmaxf(a, 1e-6f), 1.0f - 1e-6f);
}

__device__ __forceinline__ void fma4(float4& d, float a, const float4& x) {
    d.x = fmaf(a, d.x, x.x);
    d.y = fmaf(a, d.y, x.y);
    d.z = fmaf(a, d.z, x.z);
    d.w = fmaf(a, d.w, x.w);
}

// Kernel 1: L[b,c,k,:] = sum_{j=0..C-1} alpha_k^(C-1-j) * h[b, c*C+j, :]
__global__ void __launch_bounds__(128)
ema_chunk_sums(const float4* __restrict__ h4,
               const float*  __restrict__ raw_alpha,
               float4* __restrict__ lbuf) {
    const int c  = blockIdx.x % NCHUNK;
    const int b  = blockIdx.x / NCHUNK;
    const int d4 = threadIdx.x;

    float al[K_CH];
#pragma unroll
    for (int k = 0; k < K_CH; ++k) al[k] = sigmoid_clip(raw_alpha[k]);

    float4 acc[K_CH];
#pragma unroll
    for (int k = 0; k < K_CH; ++k) acc[k] = make_float4(0.f, 0.f, 0.f, 0.f);

    const float4* hp = h4 + ((size_t)b * T_LEN + (size_t)c * CHUNK) * D4 + d4;
#pragma unroll 4
    for (int j = 0; j < CHUNK; ++j) {
        float4 hv = hp[(size_t)j * D4];
#pragma unroll
        for (int k = 0; k < K_CH; ++k) fma4(acc[k], al[k], hv);
    }
#pragma unroll
    for (int k = 0; k < K_CH; ++k)
        lbuf[(((size_t)b * NCHUNK + c) * K_CH + k) * D4 + d4] = acc[k];
}

// Kernel 2: derive entering state from L prefix, rescan chunk, normalize, write.
__global__ void __launch_bounds__(128)
ema_apply(const float4* __restrict__ h4,
          const float*  __restrict__ raw_alpha,
          const float4* __restrict__ lbuf,
          float4* __restrict__ out4) {
    // reverse c order: long-prefix blocks dispatch first (tail-balance)
    const int c  = (NCHUNK - 1) - (blockIdx.x % NCHUNK);
    const int b  = blockIdx.x / NCHUNK;
    const int d4 = threadIdx.x;
    const int t0 = c * CHUNK;

    float al[K_CH], aC[K_CH];
#pragma unroll
    for (int k = 0; k < K_CH; ++k) {
        al[k] = sigmoid_clip(raw_alpha[k]);
        aC[k] = exp2f((float)CHUNK * log2f(al[k]));   // alpha^CHUNK
    }

    // ---- entering state: S = sum_{cp<c} aC^(c-1-cp) * L[b,cp,k,:]  ----
    float4 S[K_CH];
#pragma unroll
    for (int k = 0; k < K_CH; ++k) S[k] = make_float4(0.f, 0.f, 0.f, 0.f);

    const float4* lp = lbuf + ((size_t)b * NCHUNK * K_CH) * D4 + d4;
#pragma unroll 4
    for (int cp = 0; cp < c; ++cp) {
#pragma unroll
        for (int k = 0; k < K_CH; ++k) {
            float4 Lv = lp[((size_t)cp * K_CH + k) * D4];
            fma4(S[k], aC[k], Lv);
        }
    }

    // ---- rescan chunk, normalize, store ----
    float om[K_CH], pw[K_CH];
#pragma unroll
    for (int k = 0; k < K_CH; ++k) {
        om[k] = 1.0f - al[k];
        pw[k] = exp2f((float)(t0 + 1) * log2f(al[k]));  // alpha^(t+1) at j=0
    }

    const float4* hp = h4 + ((size_t)b * T_LEN + t0) * D4 + d4;
    float4* op = out4 + (((size_t)b * T_LEN + t0) * (size_t)K_CH) * D4 + d4;

#pragma unroll 2
    for (int j = 0; j < CHUNK; ++j) {
        const float4 hv = hp[(size_t)j * D4];
#pragma unroll
        for (int k = 0; k < K_CH; ++k) {
            fma4(S[k], al[k], hv);
            const float invZ = om[k] / fmaxf(1.0f - pw[k], 1e-30f);
            float4 o;
            o.x = S[k].x * invZ;
            o.y = S[k].y * invZ;
            o.z = S[k].z * invZ;
            o.w = S[k].w * invZ;
            op[((size_t)j * K_CH + k) * D4] = o;
            pw[k] *= al[k];
        }
    }
}

} // namespace

extern "C" void kernel_launch(void* const* d_in, const int* in_sizes, int n_in,
                              void* d_out, int out_size, void* d_ws, size_t ws_size,
                              hipStream_t stream)
{
    const float4* h4        = (const float4*)d_in[0];
    const float*  raw_alpha = (const float*)d_in[1];
    float4* out4 = (float4*)d_out;

    const int B = in_sizes[0] / (T_LEN * D_DIM);  // 4

    float4* lbuf = (float4*)d_ws;  // B*NCHUNK*K*D4 float4 = 4 MB

    const dim3 blk(D4);            // 128 threads
    const dim3 grid(B * NCHUNK);   // 512 blocks

    hipLaunchKernelGGL(ema_chunk_sums, grid, blk, 0, stream,
                       h4, raw_alpha, lbuf);
    hipLaunchKernelGGL(ema_apply, grid, blk, 0, stream,
                       h4, raw_alpha, lbuf, out4);
}